// Round 1
// 277.418 us; speedup vs baseline: 1.0442x; 1.0442x over previous
//
#include <hip/hip_runtime.h>
#include <hip/hip_bf16.h>

// GCN_simple: B=512 graphs x 128 nodes, FEAT=HID=512, OUT=10.
// Inputs fp32, output fp32. bf16 MFMA internally.
// R9: (1) phase-2 ping-pong staging: B buffer [65536,81920) is naturally two
//     16KB halves (waves 0-7 read rows 0..255, waves 8-15 rows 256..511).
//     Stage half-1(kt) while waves<8 compute half-0(kt); stage half-0(kt+1)
//     while waves>=8 compute half-1(kt). L2 latency hidden under the other
//     half's MFMAs instead of drained cold at a barrier. First chunk is
//     prefetched before epilogue-1. setprio(1) around phase-2 MFMA clusters
//     (wave role-split now exists -> T5 applies).
// (2) final_out fused into fused_gcn (pooled vector already in LDS; 10-wave
//     dot vs Wf writes out directly; P round-trip eliminated).
// (3) transpose + fold_w merged into one prep dispatch. 2 dispatches total.
// LDS map (bf16 elems, 160KB):
//   [0,65536)      H1 (row r at r*512; chunk cc at slot cc^(r&7))
//   [0,8192)       phase-1 A dbuf (2x8KB)      — overlaps H1 rows 0..15
//   [49152,81920)  phase-1 B dbuf (2x32KB)     — overlaps H1 rows 96..127+tail
//   [65536,73728)  phase-2 B slotA (rows 0..255,   16KB)
//   [73728,81920)  phase-2 B slotB (rows 256..511, 16KB)
//   [73728,..)     f32 scratch red[16*64], Sbuf[512] (dead while slotB live:
//                  epilogue-1 scratch use ends before first slotB stage;
//                  epilogue-2 scratch use starts after loop)

typedef __attribute__((ext_vector_type(8))) short short8;
typedef __attribute__((ext_vector_type(4))) float f32x4;
typedef __attribute__((ext_vector_type(2))) unsigned int uint2v;

#define AS_G __attribute__((address_space(1)))
#define AS_L __attribute__((address_space(3)))

__device__ __forceinline__ void gload_lds16(const void* g, void* l) {
  __builtin_amdgcn_global_load_lds((const AS_G void*)g, (AS_L void*)l, 16, 0, 0);
}

// RNE fp32->bf16 (finite), packed: b -> high 16, a -> low 16.
__device__ __forceinline__ unsigned int pack2_bf16(float a, float b) {
  unsigned int ua = __float_as_uint(a);
  unsigned int ub = __float_as_uint(b);
  ua += 0x7FFFu + ((ua >> 16) & 1u);
  ub += 0x7FFFu + ((ub >> 16) & 1u);
  return (ua >> 16) | (ub & 0xFFFF0000u);
}

__device__ __forceinline__ unsigned short bf16_rne(float a) {
  unsigned int ua = __float_as_uint(a);
  ua += 0x7FFFu + ((ua >> 16) & 1u);
  return (unsigned short)(ua >> 16);
}

__global__ __launch_bounds__(1024) void fused_gcn(
    const float* __restrict__ x,
    const __hip_bfloat16* __restrict__ W1t,   // [n][k] bf16
    const __hip_bfloat16* __restrict__ W2t,   // [n][k] bf16
    const float* __restrict__ b1,
    const float* __restrict__ b2,
    const float* __restrict__ Wf,             // [512][10] f32
    const float* __restrict__ bfv,            // [10] f32
    float* __restrict__ out)                  // [512][10] f32
{
  __shared__ __align__(16) __hip_bfloat16 smem[81920];   // 160 KB

  const int t  = threadIdx.x;
  const int g  = blockIdx.x;          // graph id 0..511
  const int wave = t >> 6;
  const int l    = t & 63;
  const int q    = l >> 4;
  const int r16  = l & 15;
  const int wm   = (wave & 1) * 64;
  const int wn   = (wave >> 1) * 64;

  // phase-1 A staging: thread (arow=t>>3, kq=t&7) loads f32x4, packs, ds_writes
  const int arow = t >> 3;
  const int kq   = t & 7;
  const float* ga = x + ((size_t)g * 128 + arow) * 512 + kq * 4;
  const int awoff = arow * 32 + (((kq >> 1) ^ ((arow >> 1) & 3)) << 3) + (kq & 1) * 4;

  // B staging (both phases): row=t>>2, slot t&3 gets global chunk (t&3)^sw(row)
  const int brow = t >> 2;
  const int bgc  = (t & 3) ^ ((brow >> 1) & 3);
  const size_t boff = (size_t)brow * 512 + bgc * 8;
  const __hip_bfloat16* g1b0 = W1t + boff;
  const __hip_bfloat16* g1b1 = g1b0 + (size_t)256 * 512;

  f32x4 acc[4][4];
#pragma unroll
  for (int i = 0; i < 4; ++i)
#pragma unroll
    for (int j = 0; j < 4; ++j)
      acc[i][j] = (f32x4)0.0f;

  // ---------------- phase 1: C1 = x_g @ W1 ----------------
  {
    f32x4 a0 = *(const f32x4*)(const void*)ga;
    gload_lds16(g1b0, smem + 49152 + wave * 512);
    gload_lds16(g1b1, smem + 49152 + 8192 + wave * 512);
    uint2v w;
    w[0] = pack2_bf16(a0[0], a0[1]);
    w[1] = pack2_bf16(a0[2], a0[3]);
    *(uint2v*)(void*)(smem + awoff) = w;
  }
  for (int kt = 0; kt < 16; ++kt) {
    const int cur = kt & 1;
    const int nxt = cur ^ 1;
    __syncthreads();

    f32x4 aN;
    if (kt < 15) {
      const int ko = (kt + 1) * 32;
      aN = *(const f32x4*)(const void*)(ga + ko);
      gload_lds16(g1b0 + ko, smem + 49152 + nxt * 16384 + wave * 512);
      gload_lds16(g1b1 + ko, smem + 49152 + nxt * 16384 + 8192 + wave * 512);
    }

    short8 af[4], bfr[4];
#pragma unroll
    for (int i = 0; i < 4; ++i) {
      const int row = wm + i * 16 + r16;
      const int c   = (q ^ ((row >> 1) & 3)) << 3;
      af[i] = *(const short8*)(const void*)(smem + cur * 4096 + row * 32 + c);
    }
#pragma unroll
    for (int j = 0; j < 4; ++j) {
      const int row = wn + j * 16 + r16;
      const int c   = (q ^ ((row >> 1) & 3)) << 3;
      bfr[j] = *(const short8*)(const void*)(smem + 49152 + cur * 16384 + row * 32 + c);
    }
#pragma unroll
    for (int i = 0; i < 4; ++i)
#pragma unroll
      for (int j = 0; j < 4; ++j)
        acc[i][j] = __builtin_amdgcn_mfma_f32_16x16x32_bf16(af[i], bfr[j], acc[i][j], 0, 0, 0);

    if (kt < 15) {
      uint2v w;
      w[0] = pack2_bf16(aN[0], aN[1]);
      w[1] = pack2_bf16(aN[2], aN[3]);
      *(uint2v*)(void*)(smem + nxt * 4096 + awoff) = w;
    }
  }
  __syncthreads();   // staging dead; epilogue-1 may write H1 anywhere

  // phase-2 B pointers + prologue prefetch of half-0(kt=0) into slotA.
  // slotA [65536,73728) is disjoint from epilogue-1 scratch (slotB region),
  // so this load flies during the whole epilogue.
  const __hip_bfloat16* g2b0 = W2t + boff;                    // rows 0..255
  const __hip_bfloat16* g2b1 = g2b0 + (size_t)256 * 512;      // rows 256..511
  gload_lds16(g2b0, smem + 65536 + wave * 512);

  float* redf = (float*)(smem + 73728);   // 16*64 f32 (4 KB)  — in slotB region
  float* Sbuf = (float*)(smem + 75776);   // 512 f32  (2 KB)

  // epilogue-1: H1 = relu(...) bf16 into LDS (C/D: col=lane&15, row=q*4+reg)
  if (g == 0) {
    // raw column sums S_c over all 128 rows
    float sj[4];
#pragma unroll
    for (int j = 0; j < 4; ++j) {
      float a = 0.0f;
#pragma unroll
      for (int i = 0; i < 4; ++i)
#pragma unroll
        for (int r = 0; r < 4; ++r)
          a += acc[i][j][r];
      a += __shfl_xor(a, 16, 64);
      a += __shfl_xor(a, 32, 64);
      sj[j] = a;
    }
    if (q == 0) {
#pragma unroll
      for (int j = 0; j < 4; ++j) redf[wave * 64 + j * 16 + r16] = sj[j];
    }
    __syncthreads();
    if (t < 512)
      Sbuf[t] = redf[((t >> 6) * 2) * 64 + (t & 63)] +
                redf[((t >> 6) * 2 + 1) * 64 + (t & 63)];
    __syncthreads();
#pragma unroll
    for (int j = 0; j < 4; ++j) {
      const int col = wn + j * 16 + r16;
      const float bv = b1[col];
      const float Sv = Sbuf[col];
#pragma unroll
      for (int i = 0; i < 4; ++i)
#pragma unroll
        for (int r = 0; r < 4; ++r) {
          const int row = wm + i * 16 + q * 4 + r;
          const float v = fmaxf((Sv + acc[i][j][r]) * (1.0f / 129.0f) + bv, 0.0f);
          const float o = __shfl_xor(v, 1, 64);
          if ((r16 & 1) == 0) {
            const int sl = (col >> 3) ^ (row & 7);
            *(unsigned int*)(void*)(smem + row * 512 + sl * 8 + (col & 7)) = pack2_bf16(v, o);
          }
        }
    }
  } else {
#pragma unroll
    for (int j = 0; j < 4; ++j) {
      const int col = wn + j * 16 + r16;
      const float bv = b1[col];
#pragma unroll
      for (int i = 0; i < 4; ++i)
#pragma unroll
        for (int r = 0; r < 4; ++r) {
          const int row = wm + i * 16 + q * 4 + r;
          const float v = fmaxf(acc[i][j][r] + bv, 0.0f);
          const float o = __shfl_xor(v, 1, 64);
          if ((r16 & 1) == 0) {
            const int sl = (col >> 3) ^ (row & 7);
            *(unsigned int*)(void*)(smem + row * 512 + sl * 8 + (col & 7)) = pack2_bf16(v, o);
          }
        }
    }
  }

  // ---------------- phase 2: C2 = H1 @ W2 (A resident in LDS) ----------------
  // Ping-pong: waves 0-7 only read B rows 0..255 (slotA), waves 8-15 only
  // rows 256..511 (slotB). Addresses identical to the old single buffer
  // (65536 + row*32 + swz) — only staging timing changes.
#pragma unroll
  for (int i = 0; i < 4; ++i)
#pragma unroll
    for (int j = 0; j < 4; ++j)
      acc[i][j] = (f32x4)0.0f;

  for (int kt = 0; kt < 16; ++kt) {
    __syncthreads();   // slotA(kt) staged; (kt=0: + H1 writes visible, scratch dead)
    // stage half-1(kt) -> slotB; consumed one barrier later (hidden under sub-1 MFMAs)
    gload_lds16(g2b1 + kt * 32, smem + 73728 + wave * 512);
    if (wave < 8) {
      short8 af[4], bfr[4];
#pragma unroll
      for (int i = 0; i < 4; ++i) {
        const int row = wm + i * 16 + r16;
        const int sl  = (kt * 4 + q) ^ (row & 7);
        af[i] = *(const short8*)(const void*)(smem + row * 512 + sl * 8);
      }
#pragma unroll
      for (int j = 0; j < 4; ++j) {
        const int row = wn + j * 16 + r16;            // < 256
        const int c   = (q ^ ((row >> 1) & 3)) << 3;
        bfr[j] = *(const short8*)(const void*)(smem + 65536 + row * 32 + c);
      }
      __builtin_amdgcn_s_setprio(1);
#pragma unroll
      for (int i = 0; i < 4; ++i)
#pragma unroll
        for (int j = 0; j < 4; ++j)
          acc[i][j] = __builtin_amdgcn_mfma_f32_16x16x32_bf16(af[i], bfr[j], acc[i][j], 0, 0, 0);
      __builtin_amdgcn_s_setprio(0);
    }
    __syncthreads();   // slotB(kt) staged; slotA reads retired
    if (kt < 15)
      gload_lds16(g2b0 + (kt + 1) * 32, smem + 65536 + wave * 512);  // half-0(kt+1) -> slotA
    if (wave >= 8) {
      short8 af[4], bfr[4];
#pragma unroll
      for (int i = 0; i < 4; ++i) {
        const int row = wm + i * 16 + r16;
        const int sl  = (kt * 4 + q) ^ (row & 7);
        af[i] = *(const short8*)(const void*)(smem + row * 512 + sl * 8);
      }
#pragma unroll
      for (int j = 0; j < 4; ++j) {
        const int row = wn + j * 16 + r16;            // >= 256
        const int c   = (q ^ ((row >> 1) & 3)) << 3;
        bfr[j] = *(const short8*)(const void*)(smem + 65536 + row * 32 + c);
      }
      __builtin_amdgcn_s_setprio(1);
#pragma unroll
      for (int i = 0; i < 4; ++i)
#pragma unroll
        for (int j = 0; j < 4; ++j)
          acc[i][j] = __builtin_amdgcn_mfma_f32_16x16x32_bf16(af[i], bfr[j], acc[i][j], 0, 0, 0);
      __builtin_amdgcn_s_setprio(0);
    }
  }
  __syncthreads();   // Bbuf dead -> scratch

  // epilogue-2: fused mean-pool of relu(C2 + b2) (block 0: fixed formula)
  float pj[4];
  if (g == 0) {
    float sj[4];
#pragma unroll
    for (int j = 0; j < 4; ++j) {
      float a = 0.0f;
#pragma unroll
      for (int i = 0; i < 4; ++i)
#pragma unroll
        for (int r = 0; r < 4; ++r)
          a += acc[i][j][r];
      a += __shfl_xor(a, 16, 64);
      a += __shfl_xor(a, 32, 64);
      sj[j] = a;
    }
    if (q == 0) {
#pragma unroll
      for (int j = 0; j < 4; ++j) redf[wave * 64 + j * 16 + r16] = sj[j];
    }
    __syncthreads();
    if (t < 512)
      Sbuf[t] = redf[((t >> 6) * 2) * 64 + (t & 63)] +
                redf[((t >> 6) * 2 + 1) * 64 + (t & 63)];
    __syncthreads();
#pragma unroll
    for (int j = 0; j < 4; ++j) {
      const float bv = b2[wn + j * 16 + r16];
      const float Sv = Sbuf[wn + j * 16 + r16];
      float a = 0.0f;
#pragma unroll
      for (int i = 0; i < 4; ++i)
#pragma unroll
        for (int r = 0; r < 4; ++r)
          a += fmaxf((Sv + acc[i][j][r]) * (1.0f / 129.0f) + bv, 0.0f);
      a += __shfl_xor(a, 16, 64);
      a += __shfl_xor(a, 32, 64);
      pj[j] = a;
    }
  } else {
#pragma unroll
    for (int j = 0; j < 4; ++j) {
      const float bv = b2[wn + j * 16 + r16];
      float a = 0.0f;
#pragma unroll
      for (int i = 0; i < 4; ++i)
#pragma unroll
        for (int r = 0; r < 4; ++r)
          a += fmaxf(acc[i][j][r] + bv, 0.0f);
      a += __shfl_xor(a, 16, 64);
      a += __shfl_xor(a, 32, 64);
      pj[j] = a;
    }
  }
  if (q == 0) {
#pragma unroll
    for (int j = 0; j < 4; ++j) redf[wave * 64 + j * 16 + r16] = pj[j];
  }
  __syncthreads();
  if (t < 512)
    Sbuf[t] =
        (redf[((t >> 6) * 2) * 64 + (t & 63)] +
         redf[((t >> 6) * 2 + 1) * 64 + (t & 63)]) * (1.0f / 128.0f);
  __syncthreads();

  // fused final_out: out[g][o] = pooled . Wf[:,o] + bfv[o]   (wave o of 10)
  if (wave < 10) {
    float s = 0.0f;
    for (int c = l; c < 512; c += 64) s += Sbuf[c] * Wf[c * 10 + wave];
#pragma unroll
    for (int off = 32; off; off >>= 1) s += __shfl_down(s, off, 64);
    if (l == 0) out[(size_t)g * 10 + wave] = s + bfv[wave];
  }
}

// prep: blocks 0..511 transpose W1/W2 -> bf16 [n][k]; blocks 512..1023 fold
// Wf[c][:] = W3[c][:]@Wlin, bfv = b3@Wlin + blin.
__global__ __launch_bounds__(1024) void prep(
    const float* __restrict__ W1, const float* __restrict__ W2,
    unsigned short* __restrict__ W1t, unsigned short* __restrict__ W2t,
    const float* __restrict__ W3, const float* __restrict__ Wlin,
    const float* __restrict__ b3, const float* __restrict__ blin,
    float* __restrict__ Wf, float* __restrict__ bfv) {
  const int b = blockIdx.x;
  if (b < 512) {
    __shared__ float tile[32][33];
    const int z  = b >> 8;
    const int by = (b >> 4) & 15;
    const int bx = b & 15;
    const float* W = z ? W2 : W1;
    unsigned short* Wt = z ? W2t : W1t;
    const int tx = threadIdx.x & 31;
    const int ty = threadIdx.x >> 5;
    tile[ty][tx] = W[(by * 32 + ty) * 512 + bx * 32 + tx];
    __syncthreads();
    Wt[(bx * 32 + ty) * 512 + by * 32 + tx] = bf16_rne(tile[tx][ty]);
  } else {
    const int c = b - 512;
    const int l = threadIdx.x;
    if (l < 64) {
      float acc[10];
#pragma unroll
      for (int o = 0; o < 10; ++o) acc[o] = 0.0f;
      for (int n = l; n < 512; n += 64) {
        const float wv = W3[c * 512 + n];
#pragma unroll
        for (int o = 0; o < 10; ++o) acc[o] += wv * Wlin[n * 10 + o];
      }
#pragma unroll
      for (int off = 32; off; off >>= 1)
#pragma unroll
        for (int o = 0; o < 10; ++o) acc[o] += __shfl_down(acc[o], off, 64);
      if (l == 0) {
#pragma unroll
        for (int o = 0; o < 10; ++o) Wf[c * 10 + o] = acc[o];
      }
      if (c < 10) {
        float s = 0.0f;
        for (int k = l; k < 512; k += 64) s += b3[k] * Wlin[k * 10 + c];
#pragma unroll
        for (int off = 32; off; off >>= 1) s += __shfl_down(s, off, 64);
        if (l == 0) bfv[c] = s + blin[c];
      }
    }
  }
}

extern "C" void kernel_launch(void* const* d_in, const int* in_sizes, int n_in,
                              void* d_out, int out_size, void* d_ws, size_t ws_size,
                              hipStream_t stream) {
  const float* x    = (const float*)d_in[0];
  const float* W1   = (const float*)d_in[1];
  const float* b1   = (const float*)d_in[2];
  const float* W2   = (const float*)d_in[3];
  const float* b2   = (const float*)d_in[4];
  const float* W3   = (const float*)d_in[5];
  const float* b3   = (const float*)d_in[6];
  const float* Wlin = (const float*)d_in[7];
  const float* blin = (const float*)d_in[8];
  float* out = (float*)d_out;

  char* ws = (char*)d_ws;
  unsigned short* W1t = (unsigned short*)ws;                 // 512 KB
  unsigned short* W2t = W1t + 512 * 512;                     // 512 KB
  float* Wf           = (float*)(W2t + 512 * 512);           // 20 KB
  float* bfv          = Wf + 512 * 10;                       // 40 B

  prep<<<1024, 1024, 0, stream>>>(W1, W2, W1t, W2t, W3, Wlin, b3, blin, Wf, bfv);

  fused_gcn<<<512, 1024, 0, stream>>>(
      x, (const __hip_bfloat16*)W1t, (const __hip_bfloat16*)W2t, b1, b2, Wf, bfv, out);
}